// Round 3
// baseline (380.129 us; speedup 1.0000x reference)
//
#include <hip/hip_runtime.h>

#define B_ 4
#define T_ 4096
#define D_ 2048
#define R_ 512
#define NPAIR (T_ - 1)
#define EPS_ 1e-12f

// ---------------- Kernel 1a: per-row L2 norms of batch 0 ----------------
__global__ __launch_bounds__(256) void row_norms_k(const float* __restrict__ x,
                                                   float* __restrict__ norms) {
    int t = blockIdx.x;
    const float4* row = (const float4*)(x + (size_t)t * D_);
    float s = 0.f;
    for (int d = threadIdx.x; d < D_ / 4; d += 256) {
        float4 v = row[d];
        s += v.x * v.x + v.y * v.y + v.z * v.z + v.w * v.w;
    }
    for (int o = 32; o > 0; o >>= 1) s += __shfl_down(s, o, 64);
    __shared__ float ws[4];
    if ((threadIdx.x & 63) == 0) ws[threadIdx.x >> 6] = s;
    __syncthreads();
    if (threadIdx.x == 0) norms[t] = sqrtf(ws[0] + ws[1] + ws[2] + ws[3]);
}

// ---------------- Kernel 1b: adjacent cosine similarities ----------------
__global__ __launch_bounds__(256) void adj_k(const float* __restrict__ x,
                                             const float* __restrict__ norms,
                                             float* __restrict__ adj) {
    int i = blockIdx.x;  // 0..NPAIR-1
    float ni = fmaxf(norms[i], EPS_);
    float nj = fmaxf(norms[i + 1], EPS_);
    const float4* r0 = (const float4*)(x + (size_t)i * D_);
    const float4* r1 = (const float4*)(x + (size_t)(i + 1) * D_);
    float s = 0.f;
    for (int d = threadIdx.x; d < D_ / 4; d += 256) {
        float4 a = r0[d];
        float4 b = r1[d];
        s += (a.x / ni) * (b.x / nj) + (a.y / ni) * (b.y / nj) +
             (a.z / ni) * (b.z / nj) + (a.w / ni) * (b.w / nj);
    }
    for (int o = 32; o > 0; o >>= 1) s += __shfl_down(s, o, 64);
    __shared__ float ws[4];
    if ((threadIdx.x & 63) == 0) ws[threadIdx.x >> 6] = s;
    __syncthreads();
    if (threadIdx.x == 0) adj[i] = ws[0] + ws[1] + ws[2] + ws[3];
}

// ---------------- Kernel 2: bitonic sort + capped greedy selection ----------------
// Keys: (descending adj, ascending index) packed so ascending u64 sort gives
// the reference's stable argsort(-adj) order.
__global__ __launch_bounds__(1024) void sort_select_k(const float* __restrict__ adj,
                                                      int* __restrict__ m_out) {
    __shared__ unsigned long long keys[T_];
    __shared__ int lds_m[T_];
    const int tid = threadIdx.x;

    for (int i = tid; i < T_; i += 1024) {
        unsigned long long key;
        if (i < NPAIR) {
            unsigned u = __float_as_uint(adj[i]);
            // map float bits -> ascending-orderable u32
            u ^= (u & 0x80000000u) ? 0xFFFFFFFFu : 0x80000000u;
            unsigned kdesc = ~u;  // descending adj
            key = ((unsigned long long)kdesc << 32) | (unsigned)i;
        } else {
            key = 0xFFFFFFFFFFFFFFFFull;  // padding sorts last
        }
        keys[i] = key;
        lds_m[i] = 0;
    }
    __syncthreads();

    // bitonic sort, ascending, 4096 elements
    for (int k = 2; k <= T_; k <<= 1) {
        for (int j = k >> 1; j > 0; j >>= 1) {
            for (int t = tid; t < T_ / 2; t += 1024) {
                int i = ((t & ~(j - 1)) << 1) | (t & (j - 1));
                int p = i | j;
                bool up = ((i & k) == 0);
                unsigned long long a = keys[i];
                unsigned long long b = keys[p];
                if ((a > b) == up) {
                    keys[i] = b;
                    keys[p] = a;
                }
            }
            __syncthreads();
        }
    }

    // Greedy capped selection. used[] lives as a 4096-bit register bitmask
    // across wave 0's lanes (lane j holds positions [j*64, j*64+64)).
    if (tid < 64) {
        const int lane = tid;
        unsigned long long used = 0ull;
        int count = 0;
        for (int kc = 0; kc < T_ && count < R_; kc += 64) {
            int myidx = (int)(unsigned)(keys[kc + lane] & 0xFFFFFFFFull);
            for (int s = 0; s < 64 && count < R_; ++s) {
                int i = __builtin_amdgcn_readlane(myidx, s);
                if ((unsigned)i >= (unsigned)NPAIR) continue;  // padding
                int j1 = i >> 6, b1 = i & 63;
                int i2 = i + 1;
                int j2 = i2 >> 6, b2 = i2 & 63;
                bool hit = ((lane == j1) && ((used >> b1) & 1ull)) ||
                           ((lane == j2) && ((used >> b2) & 1ull));
                if (__ballot(hit) == 0ull) {
                    if (lane == j1) used |= 1ull << b1;
                    if (lane == j2) used |= 1ull << b2;
                    if (lane == 0) {
                        lds_m[i] = 1;   // merge with next
                        lds_m[i2] = 2;  // merge with prev
                    }
                    ++count;
                }
            }
        }
    }
    __syncthreads();

    for (int i = tid; i < T_; i += 1024) m_out[i] = lds_m[i];
}

// ---------------- Kernel 3: pointwise merge sweep ----------------
// out[b,t,:] = x[b,t,:]                      (m[t]==0)
//            = 0.5*(x[b,t,:]+x[b,t+1,:])    (m[t]==1)
//            = 0.5*(x[b,t-1,:]+x[b,t,:])    (m[t]==2)
__global__ __launch_bounds__(256) void apply_merge_k(const float* __restrict__ x,
                                                     const int* __restrict__ m,
                                                     float* __restrict__ out) {
    const int D4 = D_ / 4;                       // 512 float4 per row
    const int total = B_ * T_ * D4;              // 8388608
    const float4* xv = (const float4*)x;
    float4* ov = (float4*)out;
    for (int idx = blockIdx.x * 256 + threadIdx.x; idx < total;
         idx += gridDim.x * 256) {
        int row = idx >> 9;         // / D4
        int t = row & (T_ - 1);
        int mm = m[t];
        float4 v = xv[idx];
        if (mm) {
            int off = (mm == 1) ? D4 : -D4;
            float4 w = xv[idx + off];
            v.x = 0.5f * (v.x + w.x);
            v.y = 0.5f * (v.y + w.y);
            v.z = 0.5f * (v.z + w.z);
            v.w = 0.5f * (v.w + w.w);
        }
        ov[idx] = v;
    }
}

extern "C" void kernel_launch(void* const* d_in, const int* in_sizes, int n_in,
                              void* d_out, int out_size, void* d_ws, size_t ws_size,
                              hipStream_t stream) {
    const float* x = (const float*)d_in[0];
    float* out = (float*)d_out;
    float* norms = (float*)d_ws;              // 4096 floats
    float* adj = norms + T_;                  // 4096 floats (4095 used)
    int* m = (int*)(adj + T_);                // 4096 ints

    row_norms_k<<<T_, 256, 0, stream>>>(x, norms);
    adj_k<<<NPAIR, 256, 0, stream>>>(x, norms, adj);
    sort_select_k<<<1, 1024, 0, stream>>>(adj, m);
    apply_merge_k<<<8192, 256, 0, stream>>>(x, m, out);
}

// Round 4
// 255.332 us; speedup vs baseline: 1.4888x; 1.4888x over previous
//
#include <hip/hip_runtime.h>

#define B_ 4
#define T_ 4096
#define D_ 2048
#define R_ 512
#define NPAIR (T_ - 1)
#define EPS_ 1e-12f

// ---------------- Kernel 1: fused norms + adjacent cosine similarity ----------------
// Block i reads rows i and i+1 of batch 0 into registers, computes both norms
// and the dot of normalized rows: adj[i] = sum (a/ni)*(b/nj)  (same per-element
// arithmetic as the reference's xn = x/norm; einsum).
__global__ __launch_bounds__(256) void adj_fused_k(const float* __restrict__ x,
                                                   float* __restrict__ adj) {
    const int i = blockIdx.x;  // 0..NPAIR-1
    const float4* r0 = (const float4*)(x + (size_t)i * D_);
    const float4* r1 = (const float4*)(x + (size_t)(i + 1) * D_);
    // D/4 = 512 float4 per row, 256 threads -> 2 each
    float4 a0 = r0[threadIdx.x], a1 = r0[threadIdx.x + 256];
    float4 b0 = r1[threadIdx.x], b1 = r1[threadIdx.x + 256];

    float sa = a0.x * a0.x + a0.y * a0.y + a0.z * a0.z + a0.w * a0.w +
               a1.x * a1.x + a1.y * a1.y + a1.z * a1.z + a1.w * a1.w;
    float sb = b0.x * b0.x + b0.y * b0.y + b0.z * b0.z + b0.w * b0.w +
               b1.x * b1.x + b1.y * b1.y + b1.z * b1.z + b1.w * b1.w;
    #pragma unroll
    for (int off = 1; off < 64; off <<= 1) {
        sa += __shfl_xor(sa, off, 64);
        sb += __shfl_xor(sb, off, 64);
    }
    __shared__ float wsa[4], wsb[4], wss[4];
    const int w = threadIdx.x >> 6;
    if ((threadIdx.x & 63) == 0) { wsa[w] = sa; wsb[w] = sb; }
    __syncthreads();
    const float ni = fmaxf(sqrtf(wsa[0] + wsa[1] + wsa[2] + wsa[3]), EPS_);
    const float nj = fmaxf(sqrtf(wsb[0] + wsb[1] + wsb[2] + wsb[3]), EPS_);

    float s = (a0.x / ni) * (b0.x / nj) + (a0.y / ni) * (b0.y / nj) +
              (a0.z / ni) * (b0.z / nj) + (a0.w / ni) * (b0.w / nj) +
              (a1.x / ni) * (b1.x / nj) + (a1.y / ni) * (b1.y / nj) +
              (a1.z / ni) * (b1.z / nj) + (a1.w / ni) * (b1.w / nj);
    #pragma unroll
    for (int off = 1; off < 64; off <<= 1) s += __shfl_xor(s, off, 64);
    if ((threadIdx.x & 63) == 0) wss[w] = s;
    __syncthreads();
    if (threadIdx.x == 0) adj[i] = wss[0] + wss[1] + wss[2] + wss[3];
}

// ---------------- Kernel 2: locally-dominant matching + radix top-512 ----------------
// Priority key (descending processing order of the reference's argsort(-adj)):
//   ka = (orderable_ascending(adj) << 32) | (NPAIR-1-i)
// so bigger ka == processed earlier (larger adj, then smaller index).
//
// Phase A: parallel locally-dominant matching == uncapped greedy matching S.
// Phase B: capped result = 512 largest-ka members of S; found by exact
//          byte-radix descent (keys unique -> no tie ambiguity).
__global__ __launch_bounds__(1024) void select_k(const float* __restrict__ adj,
                                                 int* __restrict__ m_out) {
    __shared__ unsigned long long ka[T_];
    __shared__ unsigned char state[T_];  // 0=live 1=accepted 2=dead
    __shared__ unsigned char dec[T_];
    __shared__ int mlds[T_];
    __shared__ int hist[256];
    __shared__ int scal[2];                  // [0]=live count, [1]=need
    __shared__ unsigned long long thrsh;
    const int tid = threadIdx.x;

    for (int i = tid; i < T_; i += 1024) {
        if (i < NPAIR) {
            unsigned u = __float_as_uint(adj[i]);
            u ^= (u & 0x80000000u) ? 0xFFFFFFFFu : 0x80000000u;  // ascending orderable
            ka[i] = ((unsigned long long)u << 32) | (unsigned)(NPAIR - 1 - i);
            state[i] = 0;
        } else {
            ka[i] = 0ull;
            state[i] = 2;
        }
        mlds[i] = 0;
    }
    __syncthreads();

    // ---- Phase A: locally-dominant matching rounds ----
    for (;;) {
        // decide (reads old state)
        for (int i = tid; i < NPAIR; i += 1024) {
            bool acc = false;
            if (state[i] == 0) {
                unsigned long long k = ka[i];
                bool okl = (i == 0)         || state[i - 1] != 0 || k > ka[i - 1];
                bool okr = (i == NPAIR - 1) || state[i + 1] != 0 || k > ka[i + 1];
                acc = okl && okr;
            }
            dec[i] = acc ? 1 : 0;
        }
        __syncthreads();
        // apply (each thread writes only its own state)
        int myLive = 0;
        for (int i = tid; i < NPAIR; i += 1024) {
            unsigned char st = state[i];
            if (st == 0) {
                if (dec[i]) st = 1;
                else if ((i > 0 && dec[i - 1]) || (i < NPAIR - 1 && dec[i + 1])) st = 2;
                state[i] = st;
                if (st == 0) myLive++;
            }
        }
        __syncthreads();
        if (tid == 0) scal[0] = 0;
        __syncthreads();
        #pragma unroll
        for (int off = 1; off < 64; off <<= 1) myLive += __shfl_xor(myLive, off, 64);
        if ((tid & 63) == 0 && myLive) atomicAdd(&scal[0], myLive);
        __syncthreads();
        if (scal[0] == 0) break;
    }

    // ---- Phase B: exact 512th-largest key among accepted via byte descent ----
    if (tid == 0) { thrsh = 0ull; scal[1] = R_; }
    __syncthreads();
    for (int byte = 7; byte >= 0; --byte) {
        if (tid < 256) hist[tid] = 0;
        __syncthreads();
        const int shift = byte * 8;
        for (int i = tid; i < NPAIR; i += 1024) {
            if (state[i] == 1) {
                unsigned long long k = ka[i];
                bool match = (byte == 7) || ((k >> (shift + 8)) == (thrsh >> (shift + 8)));
                if (match) atomicAdd(&hist[(int)((k >> shift) & 0xFF)], 1);
            }
        }
        __syncthreads();
        if (tid < 64) {
            const int l = tid;
            int c0 = hist[4 * l], c1 = hist[4 * l + 1], c2 = hist[4 * l + 2], c3 = hist[4 * l + 3];
            int g = c0 + c1 + c2 + c3;
            int G = g;  // inclusive suffix sum over lane groups
            #pragma unroll
            for (int off = 1; off < 64; off <<= 1) {
                int o = __shfl_down(G, off, 64);
                G += (l + off < 64) ? o : 0;
            }
            const int aboveGroup = G - g;
            const int need = scal[1];
            int ca3 = aboveGroup;
            int ca2 = ca3 + c3;
            int ca1 = ca2 + c2;
            int ca0 = ca1 + c1;
            int selv = -1, selca = 0;
            if      (ca3 < need && need <= ca3 + c3) { selv = 4 * l + 3; selca = ca3; }
            else if (ca2 < need && need <= ca2 + c2) { selv = 4 * l + 2; selca = ca2; }
            else if (ca1 < need && need <= ca1 + c1) { selv = 4 * l + 1; selca = ca1; }
            else if (ca0 < need && need <= ca0 + c0) { selv = 4 * l + 0; selca = ca0; }
            if (selv >= 0) {  // exactly one lane-bin matches globally
                thrsh |= ((unsigned long long)(unsigned)selv) << shift;
                scal[1] = need - selca;
            }
        }
        __syncthreads();
    }

    // ---- mark merges: selected = accepted && ka >= thrsh (exactly R_) ----
    const unsigned long long thr = thrsh;
    for (int i = tid; i < NPAIR; i += 1024) {
        if (state[i] == 1 && ka[i] >= thr) {
            mlds[i] = 1;       // merge with next
            mlds[i + 1] = 2;   // merge with prev (disjoint: pairs non-overlapping)
        }
    }
    __syncthreads();
    for (int i = tid; i < T_; i += 1024) m_out[i] = mlds[i];
}

// ---------------- Kernel 3: pointwise merge sweep ----------------
__global__ __launch_bounds__(256) void apply_merge_k(const float* __restrict__ x,
                                                     const int* __restrict__ m,
                                                     float* __restrict__ out) {
    const int D4 = D_ / 4;          // 512 float4 per row
    const int total = B_ * T_ * D4; // 8388608
    const float4* xv = (const float4*)x;
    float4* ov = (float4*)out;
    for (int idx = blockIdx.x * 256 + threadIdx.x; idx < total;
         idx += gridDim.x * 256) {
        int row = idx >> 9;
        int t = row & (T_ - 1);
        int mm = m[t];
        float4 v = xv[idx];
        if (mm) {
            int off = (mm == 1) ? D4 : -D4;
            float4 w = xv[idx + off];
            v.x = 0.5f * (v.x + w.x);
            v.y = 0.5f * (v.y + w.y);
            v.z = 0.5f * (v.z + w.z);
            v.w = 0.5f * (v.w + w.w);
        }
        ov[idx] = v;
    }
}

extern "C" void kernel_launch(void* const* d_in, const int* in_sizes, int n_in,
                              void* d_out, int out_size, void* d_ws, size_t ws_size,
                              hipStream_t stream) {
    const float* x = (const float*)d_in[0];
    float* out = (float*)d_out;
    float* adj = (float*)d_ws;      // 4096 floats
    int* m = (int*)(adj + T_);      // 4096 ints

    adj_fused_k<<<NPAIR, 256, 0, stream>>>(x, adj);
    select_k<<<1, 1024, 0, stream>>>(adj, m);
    apply_merge_k<<<8192, 256, 0, stream>>>(x, m, out);
}